// Round 12
// baseline (257.531 us; speedup 1.0000x reference)
//
#include <hip/hip_runtime.h>

// GCN layer: out = relu(segment_sum(features[edge_src], edge_dst) @ W + b)
// N=100000, E=1600000, D=F=128.
//
// Round-19 structure (round-18 post-mortem: megaprep 83us at occ 33% --
// the 109KB LDS union forces 1 block/CU; 583 long-latency blocks in 2.3
// serial rounds. accum is ~6.2 TB/s L2-level traffic = near fabric ceiling.
// Fix megaprep occupancy: 4-way bucket-split fill -> 34.8KB LDS union ->
// 2 blocks/CU (thread cap)):
//  0) wsplit:   W fp32 -> split-bf16 Wht/Wlt [col][k]; zeroes ovf_cnt.
//  1) megaprep: fill role (bid < 4*NCH): block (c=bid>>2, q=bid&3) bins
//               ONLY buckets [512q, 512q+512) of chunk c (q = dst>>15 is a
//               free shift) into 32.8KB LDS cells, then streams them to the
//               chunk-major gslot sub-range (contiguous int4). Siblings
//               share edge-chunk reads via adjacent bids (L2 reuse).
//               gemmy role (bid >= 4*NCH): Y = X @ W, MFMA split-bf16,
//               256 rows/block (byte-identical to R18).
//  2) accum:    proven 64x64 half-tile kernel, chunk-major sweep
//               (byte-identical to R18).

constexpr int D     = 128;   // input feature dim
constexpr int F     = 128;   // output feature dim
constexpr int NCH   = 192;   // edge chunks
constexpr int CAPC  = 16;    // cell capacity = one 64B line (lambda ~5.33)
constexpr int NBQ   = 512;   // buckets per fill sub-block (N < 4*512*64)
constexpr int OVCAP = 16384; // overflow list capacity
constexpr int LCAP  = 120;   // per-owner list cap (Poisson(64) + 7 sd)

typedef short bf16x8 __attribute__((ext_vector_type(8)));
typedef float f32x4  __attribute__((ext_vector_type(4)));

__device__ __forceinline__ unsigned bf16_rne(float f) {
  unsigned u = __float_as_uint(f);
  return (u + 0x7FFFu + ((u >> 16) & 1u)) >> 16;
}

// ---------------------------------------------------------------------------
// Kernel 0: W [k][c] fp32 -> transposed split-bf16 Wht/Wlt [c][k].
// Also zeroes ovf_cnt.
// ---------------------------------------------------------------------------
__global__ __launch_bounds__(256) void wsplit_kernel(
    const float* __restrict__ W,
    unsigned short* __restrict__ Wht,
    unsigned short* __restrict__ Wlt,
    int* __restrict__ ovf_cnt) {
  int i = blockIdx.x * 256 + threadIdx.x;   // [0, 16384)
  if (i == 0) *ovf_cnt = 0;
  int k = i >> 7;
  int c = i & 127;
  float w = W[i];
  unsigned h = bf16_rne(w);
  float hf = __uint_as_float(h << 16);
  unsigned l = bf16_rne(w - hf);
  Wht[c * 128 + k] = (unsigned short)h;
  Wlt[c * 128 + k] = (unsigned short)l;
}

// ---------------------------------------------------------------------------
// Kernel 1 (megaprep): 4-way-split fill role || gemmy role.
// LDS union: fill cells 32KB + lcnt 2KB = 34816 B | gemmy cst 33792 B.
// ---------------------------------------------------------------------------
__global__ __launch_bounds__(1024) void megaprep_kernel(
    const int* __restrict__ src,
    const int* __restrict__ dst,
    int* __restrict__ gcnt,
    int* __restrict__ gslot,           // CHUNK-MAJOR: [c][bucket][slot]
    int* __restrict__ ovf_cnt,
    int2* __restrict__ ovf,
    const float* __restrict__ X,
    const unsigned short* __restrict__ Wht,
    const unsigned short* __restrict__ Wlt,
    uint2* __restrict__ Y,             // [N] rows of 32 uint2 (128 bf16)
    int E, int NB, int CH, int N) {
  __shared__ __align__(16) char smem[NBQ * 16 * 4 + NBQ * 4];  // 34816 B
  int bid = blockIdx.x;
  int tid = threadIdx.x;

  if (bid < 4 * NCH) {
    // ---- fill role: bin buckets [512q, 512q+512) of chunk c ----
    int* cells = (int*)smem;                  // [NBQ][16]
    int* lcnt  = (int*)(smem + NBQ * 16 * 4); // [NBQ]
    int c = bid >> 2;                         // chunk (siblings adjacent)
    int q = bid & 3;                          // bucket quarter
    for (int i = tid; i < NBQ; i += 1024) lcnt[i] = 0;
    __syncthreads();

    int e0 = c * CH;
    int e1 = min(E, e0 + CH);
    for (int e = e0 + tid; e < e1; e += 1024) {
      int t = dst[e];
      int s = src[e];
      if ((t >> 15) == q) {                   // bucket>>9 == q
        int local = (t >> 6) & (NBQ - 1);     // bucket - 512q
        int entry = s | ((t & 63) << 17);
        int pos = atomicAdd(&lcnt[local], 1); // LDS int atomic (fast)
        if (pos < CAPC) {
          cells[local * CAPC + pos] = entry;  // LDS banked store
        } else {
          int gp = atomicAdd(ovf_cnt, 1);     // rare (~12 expected total)
          if (gp < OVCAP) ovf[gp] = make_int2(entry, t >> 6);
        }
      }
    }
    __syncthreads();

    // Streaming flush of this quarter's contiguous gslot sub-range.
    int qlo = q * NBQ;
    int qn = min(NB - qlo, NBQ);
    if (qn > 0) {
      int nb4 = (qn * CAPC) >> 2;             // int4 count
      int4* g4 = (int4*)(gslot + ((size_t)c * NB + qlo) * CAPC);
      const int4* c4p = (const int4*)cells;
      for (int i = tid; i < nb4; i += 1024) g4[i] = c4p[i];
      for (int i = tid; i < qn; i += 1024)
        gcnt[(size_t)c * NB + qlo + i] = lcnt[i];
    }
    return;
  }

  // ---- gemmy role: Y = X @ W, 16 waves x 16 rows = 256 rows/block ----
  float* cst = (float*)smem;           // 64x132 staging (33 KB), 4 phases
  int lane = tid & 63;
  int wv = tid >> 6;                   // wave 0..15
  int r = lane & 15;
  int g = lane >> 4;
  int unit = bid - 4 * NCH;
  int rowbase = unit * 256;
  int row = rowbase + wv * 16 + r;
  const float* xrow = X + (size_t)min(row, N - 1) * 128;

  f32x4 acc[8];
#pragma unroll
  for (int ct = 0; ct < 8; ++ct) acc[ct] = (f32x4){0.f, 0.f, 0.f, 0.f};

#pragma unroll
  for (int ks = 0; ks < 4; ++ks) {
    int k0 = ks * 32 + g * 8;
    float xf[8];
    *(float4*)&xf[0] = *(const float4*)(xrow + k0);
    *(float4*)&xf[4] = *(const float4*)(xrow + k0 + 4);
    union { bf16x8 v; unsigned u4[4]; } ahi, alo;
#pragma unroll
    for (int p = 0; p < 4; ++p) {
      unsigned h0 = bf16_rne(xf[2 * p]);
      unsigned h1 = bf16_rne(xf[2 * p + 1]);
      float f0 = __uint_as_float(h0 << 16);
      float f1 = __uint_as_float(h1 << 16);
      unsigned l0 = bf16_rne(xf[2 * p] - f0);
      unsigned l1 = bf16_rne(xf[2 * p + 1] - f1);
      ahi.u4[p] = h0 | (h1 << 16);
      alo.u4[p] = l0 | (l1 << 16);
    }
#pragma unroll
    for (int ct = 0; ct < 8; ++ct) {
      size_t bo = (size_t)(ct * 16 + r) * 128 + k0;   // 16B-aligned
      bf16x8 bh = *(const bf16x8*)(Wht + bo);
      bf16x8 bl = *(const bf16x8*)(Wlt + bo);
      acc[ct] = __builtin_amdgcn_mfma_f32_16x16x32_bf16(ahi.v, bh, acc[ct], 0, 0, 0);
      acc[ct] = __builtin_amdgcn_mfma_f32_16x16x32_bf16(alo.v, bh, acc[ct], 0, 0, 0);
      acc[ct] = __builtin_amdgcn_mfma_f32_16x16x32_bf16(ahi.v, bl, acc[ct], 0, 0, 0);
    }
  }

  // 4 phases: waves [4h,4h+4) stage 64 rows into cst, all threads write out.
#pragma unroll
  for (int h = 0; h < 4; ++h) {
    if ((wv >> 2) == h) {
      int lwv = wv & 3;                // 0..3 within phase
#pragma unroll
      for (int ct = 0; ct < 8; ++ct) {
        int col = ct * 16 + r;
#pragma unroll
        for (int v = 0; v < 4; ++v)
          cst[(lwv * 16 + g * 4 + v) * 132 + col] = acc[ct][v];
      }
    }
    __syncthreads();
    int c4 = tid & 31;
#pragma unroll
    for (int it = 0; it < 2; ++it) {
      int i = it * 1024 + tid;
      int rl = i >> 5;                 // 0..63
      int orow = rowbase + h * 64 + rl;
      if (orow < N) {
        float4 cv = *(const float4*)&cst[rl * 132 + c4 * 4];
        uint2 o;
        o.x = bf16_rne(cv.x) | (bf16_rne(cv.y) << 16);
        o.y = bf16_rne(cv.z) | (bf16_rne(cv.w) << 16);
        Y[(size_t)orow * 32 + c4] = o;
      }
    }
    __syncthreads();
  }
}

// ---------------------------------------------------------------------------
// Kernel 2: feature-split accumulate (byte-identical to R18).
// ---------------------------------------------------------------------------
__global__ __launch_bounds__(256) void accum_kernel(
    const uint2* __restrict__ yb,      // bf16 Y, row = 32 uint2
    const int* __restrict__ gcnt,
    const int* __restrict__ gslot,     // CHUNK-MAJOR: [c][bucket][slot]
    const int* __restrict__ ovf_cnt,
    const int2* __restrict__ ovf,
    const float* __restrict__ b,
    float* __restrict__ out,
    int N, int NB) {
  __shared__ float hl[64 * 64];           // 16 KB half-tile accumulator
  __shared__ int ccnt[NCH];               // clamped per-chunk counts
  __shared__ int lists[16 * LCAP];        // per-owner entry lists (7.5 KB)
  __shared__ int lcount[16];

  int bid = blockIdx.x;
  int bb = bid >> 1;                      // bucket
  int fh = bid & 1;                       // feature half
  int tid = threadIdx.x;
  float4* hl4 = (float4*)hl;

  // ---- Stage A: zero hl, stage counts ----
  float4 z4 = make_float4(0.f, 0.f, 0.f, 0.f);
#pragma unroll
  for (int i = 0; i < 4; ++i) hl4[i * 256 + tid] = z4;
  if (tid < NCH) ccnt[tid] = min(gcnt[(size_t)tid * NB + bb], CAPC);
  if (tid < 16) lcount[tid] = 0;
  __syncthreads();

  // ---- Stage B: sweep this bucket's cells (chunk-major: 192 x 64B lines) --
  for (int i0 = 0; i0 < NCH * CAPC; i0 += 256) {
    int i = i0 + tid;
    int c = i >> 4;                       // chunk
    int slot = i & (CAPC - 1);
    int entry = gslot[((size_t)c * NB + bb) * CAPC + slot];
    if (slot < ccnt[c]) {
      int o = (entry >> 17) & 15;
      int pos = atomicAdd(&lcount[o], 1);
      if (pos < LCAP) lists[o * LCAP + pos] = entry;
    }
  }
  __syncthreads();

  // ---- Stage D: group g accumulates rows dl&15==g (race-free b128 RMW) ----
  int l = tid & 15;   // lane in group; owns floats [4l,4l+4) of the half-row
  int g = tid >> 4;   // group 0..15
  int n = min(lcount[g], LCAP);
  const int* Lg = &lists[g * LCAP];
  const uint2* ybh = yb + fh * 16;       // half-row base

  int j = 0;
  for (; j + 16 <= n; j += 16) {
    uint2 v[16];
    int en[16];
#pragma unroll
    for (int k = 0; k < 16; ++k) {
      en[k] = Lg[j + k];                                  // LDS broadcast
      v[k] = ybh[(size_t)(en[k] & 0x1FFFF) * 32 + l];     // 8B bf16x4 gather
    }
#pragma unroll
    for (int k = 0; k < 16; ++k) {
      int dl = (en[k] >> 17) & 63;
      float4 h = hl4[dl * 16 + l];
      h.x += __uint_as_float(v[k].x << 16);
      h.y += __uint_as_float(v[k].x & 0xFFFF0000u);
      h.z += __uint_as_float(v[k].y << 16);
      h.w += __uint_as_float(v[k].y & 0xFFFF0000u);
      hl4[dl * 16 + l] = h;
    }
  }
  for (; j + 4 <= n; j += 4) {
    uint2 v[4];
    int en[4];
#pragma unroll
    for (int k = 0; k < 4; ++k) {
      en[k] = Lg[j + k];
      v[k] = ybh[(size_t)(en[k] & 0x1FFFF) * 32 + l];
    }
#pragma unroll
    for (int k = 0; k < 4; ++k) {
      int dl = (en[k] >> 17) & 63;
      float4 h = hl4[dl * 16 + l];
      h.x += __uint_as_float(v[k].x << 16);
      h.y += __uint_as_float(v[k].x & 0xFFFF0000u);
      h.z += __uint_as_float(v[k].y << 16);
      h.w += __uint_as_float(v[k].y & 0xFFFF0000u);
      hl4[dl * 16 + l] = h;
    }
  }
  for (; j < n; ++j) {
    int e = Lg[j];
    uint2 v = ybh[(size_t)(e & 0x1FFFF) * 32 + l];
    int dl = (e >> 17) & 63;
    float4 h = hl4[dl * 16 + l];
    h.x += __uint_as_float(v.x << 16);
    h.y += __uint_as_float(v.x & 0xFFFF0000u);
    h.z += __uint_as_float(v.y << 16);
    h.w += __uint_as_float(v.y & 0xFFFF0000u);
    hl4[dl * 16 + l] = h;
  }

  // ---- Overflow replay (expected ~12 entries globally), owner-routed ----
  __syncthreads();                       // stage D done; lists reusable
  int nov = min(*ovf_cnt, OVCAP);
  if (nov > 0) {
    int2* ovbuf = (int2*)lists;          // reuse lists memory (<=800 int2)
    for (int base = 0; base < nov; base += 800) {
      int m = min(nov - base, 800);
      for (int i = tid; i < m; i += 256) ovbuf[i] = ovf[base + i];
      __syncthreads();
      for (int i = 0; i < m; ++i) {
        int2 oe = ovbuf[i];
        if (oe.y == bb && (((oe.x >> 17) & 15) == g)) {
          uint2 v = ybh[(size_t)(oe.x & 0x1FFFF) * 32 + l];
          int dl = (oe.x >> 17) & 63;
          float4 h = hl4[dl * 16 + l];
          h.x += __uint_as_float(v.x << 16);
          h.y += __uint_as_float(v.x & 0xFFFF0000u);
          h.z += __uint_as_float(v.y << 16);
          h.w += __uint_as_float(v.y & 0xFFFF0000u);
          hl4[dl * 16 + l] = h;
        }
      }
      __syncthreads();
    }
  }
  __syncthreads();

  // ---- Stage E': out = relu(hl + b), coalesced float4 stores ----
  int c4 = tid & 15;                     // float4 col within half-row
  float4 bv = ((const float4*)b)[fh * 16 + c4];
  int row0 = bb * 64;
#pragma unroll
  for (int it = 0; it < 4; ++it) {
    int i = it * 256 + tid;
    int rl = i >> 4;                     // 0..63
    int row = row0 + rl;
    if (row < N) {
      float4 h = hl4[rl * 16 + c4];
      float4 o;
      o.x = fmaxf(h.x + bv.x, 0.f);
      o.y = fmaxf(h.y + bv.y, 0.f);
      o.z = fmaxf(h.z + bv.z, 0.f);
      o.w = fmaxf(h.w + bv.w, 0.f);
      ((float4*)out)[(size_t)row * (F / 4) + fh * 16 + c4] = o;
    }
  }
}

// ---------------------------------------------------------------------------
extern "C" void kernel_launch(void* const* d_in, const int* in_sizes, int n_in,
                              void* d_out, int out_size, void* d_ws, size_t ws_size,
                              hipStream_t stream) {
  const float* feat = (const float*)d_in[0];   // [N, D]
  const float* W    = (const float*)d_in[1];   // [D, F]
  const float* bv   = (const float*)d_in[2];   // [F]
  const int* src    = (const int*)d_in[3];     // [E]
  const int* dst    = (const int*)d_in[4];     // [E]

  int N = in_sizes[0] / D;
  int E = in_sizes[3];

  int NB = (N + 63) / 64;                      // buckets (1563; <= 4*NBQ)
  int CH = (E + NCH - 1) / NCH;                // edges per chunk (8334)
  int NU = (N + 255) / 256;                    // gemmy units (391)

  // Workspace layout (ws >= 51.2MB known from round 1):
  //   yb      [N*F bf16]           @ 0        (25.6MB)  <- Y = X@W
  //   gcnt    [NCH*NB ints]        @ 26MB     (~1.2MB)
  //   ovf_cnt [1 int]              @ 28MB
  //   ovf     [OVCAP int2]         @ 28MB+256 (128KB)
  //   gslot   [NCH*NB*CAPC ints]   @ 29MB     (19.2MB, chunk-major)
  //   Wht/Wlt [128*128 bf16 x2]    @ 50MB     (64KB)
  uint2* yb     = (uint2*)d_ws;
  int* gcnt     = (int*)((char*)d_ws + (26u << 20));
  int* ovf_cnt  = (int*)((char*)d_ws + (28u << 20));
  int2* ovf     = (int2*)((char*)d_ws + (28u << 20) + 256);
  int* gslot    = (int*)((char*)d_ws + (29u << 20));
  unsigned short* Wht = (unsigned short*)((char*)d_ws + (50u << 20));
  unsigned short* Wlt = Wht + 128 * 128;

  float* out = (float*)d_out;

  wsplit_kernel<<<64, 256, 0, stream>>>(W, Wht, Wlt, ovf_cnt);

  megaprep_kernel<<<4 * NCH + NU, 1024, 0, stream>>>(
      src, dst, gcnt, gslot, ovf_cnt, ovf, feat, Wht, Wlt, yb, E, NB, CH, N);

  accum_kernel<<<2 * NB, 256, 0, stream>>>(yb, gcnt, gslot, ovf_cnt, ovf,
                                           bv, out, N, NB);
}

// Round 13
// 197.220 us; speedup vs baseline: 1.3058x; 1.3058x over previous
//
#include <hip/hip_runtime.h>

// GCN layer: out = relu(segment_sum(features[edge_src], edge_dst) @ W + b)
// N=100000, E=1600000, D=F=128.
//
// Round-20 structure (round-19 post-mortem: 4-way bucket-split fill
// REGRESSED -- occupancy stayed ~35% (2048-thread/CU cap, not LDS, binds)
// while edge re-reads added work. REVERT fill to R18's proven form.
// R18 budget: kernels ~168us of a 243.5us total -> ~75us of dispatch
// boundaries. Kill one: fold wsplit INTO the gemmy role):
//  0) hipMemsetAsync zeroes ovf_cnt (SDMA, proven harness-safe in R0-R7).
//  1) megaprep: fill role (bid < NCH): R18's exact LDS binning -- bin 8334
//               edges into [NB x 16] LDS cells (~105KB), stream to chunk-
//               major gslot with coalesced int4 (no write-allocate).
//               gemmy role (bid >= NCH): NEW prologue builds split-bf16
//               Whi/Wlo [128][136] in LDS from fp32 W (64KB L2-resident,
//               16 elems/thread, pad->2-way bank alias = free), then the
//               proven MFMA split-bf16 Y = X @ W, 256 rows/block.
//               LDS union: max(108800 fill, 103424 gemmy) = 108800 (=R18).
//  2) accum:    byte-identical R18 kernel (64x64 half-tile, chunk-major
//               stage-B sweep, 16 owner classes, race-free b128 LDS RMW).

constexpr int D     = 128;   // input feature dim
constexpr int F     = 128;   // output feature dim
constexpr int NCH   = 192;   // edge chunks (= fill role blocks)
constexpr int CAPC  = 16;    // cell capacity = one 64B line (lambda ~5.33)
constexpr int NBF   = 1600;  // max buckets for LDS binning (N <= 102400)
constexpr int OVCAP = 16384; // overflow list capacity
constexpr int LCAP  = 120;   // per-owner list cap (Poisson(64) + 7 sd)
constexpr int WSTR  = 136;   // padded LDS row stride for W tables (bf16)

typedef short bf16x8 __attribute__((ext_vector_type(8)));
typedef float f32x4  __attribute__((ext_vector_type(4)));

__device__ __forceinline__ unsigned bf16_rne(float f) {
  unsigned u = __float_as_uint(f);
  return (u + 0x7FFFu + ((u >> 16) & 1u)) >> 16;
}

// ---------------------------------------------------------------------------
// Kernel 1 (megaprep): fill role (LDS binning + streaming flush) ||
//                      gemmy role (in-LDS W split + MFMA split-bf16).
// ---------------------------------------------------------------------------
__global__ __launch_bounds__(1024) void megaprep_kernel(
    const int* __restrict__ src,
    const int* __restrict__ dst,
    int* __restrict__ gcnt,
    int* __restrict__ gslot,           // CHUNK-MAJOR: [c][bucket][slot]
    int* __restrict__ ovf_cnt,
    int2* __restrict__ ovf,
    const float* __restrict__ X,
    const float* __restrict__ W,       // [k][c] fp32
    uint2* __restrict__ Y,             // [N] rows of 32 uint2 (128 bf16)
    int E, int NB, int CH, int N) {
  __shared__ __align__(16) char smem[NBF * 16 * 4 + NBF * 4];  // 108800 B
  int bid = blockIdx.x;
  int tid = threadIdx.x;

  if (bid < NCH) {
    // ---- fill role: LDS binning, then contiguous flush (exact R18) ----
    int* cells = (int*)smem;                  // [NB][16]
    int* lcnt  = (int*)(smem + NBF * 16 * 4); // [NB]
    int c = bid;
    for (int i = tid; i < NB; i += 1024) lcnt[i] = 0;
    __syncthreads();

    int e0 = c * CH;
    int e1 = min(E, e0 + CH);
    for (int e = e0 + tid; e < e1; e += 1024) {
      int t = dst[e];
      int s = src[e];
      int bucket = t >> 6;
      int entry = s | ((t & 63) << 17);
      int pos = atomicAdd(&lcnt[bucket], 1);  // LDS int atomic (fast)
      if (pos < CAPC) {
        cells[bucket * CAPC + pos] = entry;   // LDS banked store
      } else {
        int gp = atomicAdd(ovf_cnt, 1);       // rare (~12 expected total)
        if (gp < OVCAP) ovf[gp] = make_int2(entry, bucket);
      }
    }
    __syncthreads();

    // Streaming flush: full-line coalesced int4 stores, no write-allocate.
    {
      int nb4 = (NB * CAPC) >> 2;             // int4 count
      int4* g4 = (int4*)(gslot + (size_t)c * NB * CAPC);
      const int4* c4p = (const int4*)cells;
      for (int i = tid; i < nb4; i += 1024) g4[i] = c4p[i];
    }
    for (int i = tid; i < NB; i += 1024)
      gcnt[(size_t)c * NB + i] = lcnt[i];
    return;
  }

  // ---- gemmy role: build W tables in LDS, then Y = X @ W ----
  unsigned short* whi = (unsigned short*)smem;            // [128][WSTR] 34816B
  unsigned short* wlo = (unsigned short*)(smem + 34816);  // [128][WSTR] 34816B
  float* cst = (float*)(smem + 69632);                    // 64x132 f32 33792B

  // Prologue: W [k][c] fp32 -> whi/wlo [c][k] bf16 (transposed, padded).
  for (int i = tid; i < 128 * 128; i += 1024) {
    int k = i >> 7;
    int c = i & 127;
    float w = W[i];
    unsigned h = bf16_rne(w);
    float hf = __uint_as_float(h << 16);
    unsigned lo = bf16_rne(w - hf);
    whi[c * WSTR + k] = (unsigned short)h;
    wlo[c * WSTR + k] = (unsigned short)lo;
  }
  __syncthreads();

  int lane = tid & 63;
  int wv = tid >> 6;                   // wave 0..15
  int r = lane & 15;
  int g = lane >> 4;
  int unit = bid - NCH;
  int rowbase = unit * 256;
  int row = rowbase + wv * 16 + r;
  const float* xrow = X + (size_t)min(row, N - 1) * 128;

  f32x4 acc[8];
#pragma unroll
  for (int ct = 0; ct < 8; ++ct) acc[ct] = (f32x4){0.f, 0.f, 0.f, 0.f};

#pragma unroll
  for (int ks = 0; ks < 4; ++ks) {
    int k0 = ks * 32 + g * 8;
    float xf[8];
    *(float4*)&xf[0] = *(const float4*)(xrow + k0);
    *(float4*)&xf[4] = *(const float4*)(xrow + k0 + 4);
    union { bf16x8 v; unsigned u4[4]; } ahi, alo;
#pragma unroll
    for (int p = 0; p < 4; ++p) {
      unsigned h0 = bf16_rne(xf[2 * p]);
      unsigned h1 = bf16_rne(xf[2 * p + 1]);
      float f0 = __uint_as_float(h0 << 16);
      float f1 = __uint_as_float(h1 << 16);
      unsigned l0 = bf16_rne(xf[2 * p] - f0);
      unsigned l1 = bf16_rne(xf[2 * p + 1] - f1);
      ahi.u4[p] = h0 | (h1 << 16);
      alo.u4[p] = l0 | (l1 << 16);
    }
#pragma unroll
    for (int ct = 0; ct < 8; ++ct) {
      int bo = (ct * 16 + r) * WSTR + k0;      // 16B-aligned (WSTR*2=272)
      bf16x8 bh = *(const bf16x8*)(whi + bo);  // LDS, ~2-way alias (free)
      bf16x8 bl = *(const bf16x8*)(wlo + bo);
      acc[ct] = __builtin_amdgcn_mfma_f32_16x16x32_bf16(ahi.v, bh, acc[ct], 0, 0, 0);
      acc[ct] = __builtin_amdgcn_mfma_f32_16x16x32_bf16(alo.v, bh, acc[ct], 0, 0, 0);
      acc[ct] = __builtin_amdgcn_mfma_f32_16x16x32_bf16(ahi.v, bl, acc[ct], 0, 0, 0);
    }
  }

  // 4 phases: waves [4h,4h+4) stage 64 rows into cst, all threads write out.
#pragma unroll
  for (int h = 0; h < 4; ++h) {
    __syncthreads();                   // cst overlaps nothing live (W tables
                                       // stay resident below 69632B)
    if ((wv >> 2) == h) {
      int lwv = wv & 3;                // 0..3 within phase
#pragma unroll
      for (int ct = 0; ct < 8; ++ct) {
        int col = ct * 16 + r;
#pragma unroll
        for (int v = 0; v < 4; ++v)
          cst[(lwv * 16 + g * 4 + v) * 132 + col] = acc[ct][v];
      }
    }
    __syncthreads();
    int c4 = tid & 31;
#pragma unroll
    for (int it = 0; it < 2; ++it) {
      int i = it * 1024 + tid;
      int rl = i >> 5;                 // 0..63
      int orow = rowbase + h * 64 + rl;
      if (orow < N) {
        float4 cv = *(const float4*)&cst[rl * 132 + c4 * 4];
        uint2 o;
        o.x = bf16_rne(cv.x) | (bf16_rne(cv.y) << 16);
        o.y = bf16_rne(cv.z) | (bf16_rne(cv.w) << 16);
        Y[(size_t)orow * 32 + c4] = o;
      }
    }
  }
}

// ---------------------------------------------------------------------------
// Kernel 2: feature-split accumulate (byte-identical to R18).
// ---------------------------------------------------------------------------
__global__ __launch_bounds__(256) void accum_kernel(
    const uint2* __restrict__ yb,      // bf16 Y, row = 32 uint2
    const int* __restrict__ gcnt,
    const int* __restrict__ gslot,     // CHUNK-MAJOR: [c][bucket][slot]
    const int* __restrict__ ovf_cnt,
    const int2* __restrict__ ovf,
    const float* __restrict__ b,
    float* __restrict__ out,
    int N, int NB) {
  __shared__ float hl[64 * 64];           // 16 KB half-tile accumulator
  __shared__ int ccnt[NCH];               // clamped per-chunk counts
  __shared__ int lists[16 * LCAP];        // per-owner entry lists (7.5 KB)
  __shared__ int lcount[16];

  int bid = blockIdx.x;
  int bb = bid >> 1;                      // bucket
  int fh = bid & 1;                       // feature half
  int tid = threadIdx.x;
  float4* hl4 = (float4*)hl;

  // ---- Stage A: zero hl, stage counts ----
  float4 z4 = make_float4(0.f, 0.f, 0.f, 0.f);
#pragma unroll
  for (int i = 0; i < 4; ++i) hl4[i * 256 + tid] = z4;
  if (tid < NCH) ccnt[tid] = min(gcnt[(size_t)tid * NB + bb], CAPC);
  if (tid < 16) lcount[tid] = 0;
  __syncthreads();

  // ---- Stage B: sweep this bucket's cells (chunk-major: 192 x 64B lines) --
  for (int i0 = 0; i0 < NCH * CAPC; i0 += 256) {
    int i = i0 + tid;
    int c = i >> 4;                       // chunk
    int slot = i & (CAPC - 1);
    int entry = gslot[((size_t)c * NB + bb) * CAPC + slot];
    if (slot < ccnt[c]) {
      int o = (entry >> 17) & 15;
      int pos = atomicAdd(&lcount[o], 1);
      if (pos < LCAP) lists[o * LCAP + pos] = entry;
    }
  }
  __syncthreads();

  // ---- Stage D: group g accumulates rows dl&15==g (race-free b128 RMW) ----
  int l = tid & 15;   // lane in group; owns floats [4l,4l+4) of the half-row
  int g = tid >> 4;   // group 0..15
  int n = min(lcount[g], LCAP);
  const int* Lg = &lists[g * LCAP];
  const uint2* ybh = yb + fh * 16;       // half-row base

  int j = 0;
  for (; j + 16 <= n; j += 16) {
    uint2 v[16];
    int en[16];
#pragma unroll
    for (int k = 0; k < 16; ++k) {
      en[k] = Lg[j + k];                                  // LDS broadcast
      v[k] = ybh[(size_t)(en[k] & 0x1FFFF) * 32 + l];     // 8B bf16x4 gather
    }
#pragma unroll
    for (int k = 0; k < 16; ++k) {
      int dl = (en[k] >> 17) & 63;
      float4 h = hl4[dl * 16 + l];
      h.x += __uint_as_float(v[k].x << 16);
      h.y += __uint_as_float(v[k].x & 0xFFFF0000u);
      h.z += __uint_as_float(v[k].y << 16);
      h.w += __uint_as_float(v[k].y & 0xFFFF0000u);
      hl4[dl * 16 + l] = h;
    }
  }
  for (; j + 4 <= n; j += 4) {
    uint2 v[4];
    int en[4];
#pragma unroll
    for (int k = 0; k < 4; ++k) {
      en[k] = Lg[j + k];
      v[k] = ybh[(size_t)(en[k] & 0x1FFFF) * 32 + l];
    }
#pragma unroll
    for (int k = 0; k < 4; ++k) {
      int dl = (en[k] >> 17) & 63;
      float4 h = hl4[dl * 16 + l];
      h.x += __uint_as_float(v[k].x << 16);
      h.y += __uint_as_float(v[k].x & 0xFFFF0000u);
      h.z += __uint_as_float(v[k].y << 16);
      h.w += __uint_as_float(v[k].y & 0xFFFF0000u);
      hl4[dl * 16 + l] = h;
    }
  }
  for (; j < n; ++j) {
    int e = Lg[j];
    uint2 v = ybh[(size_t)(e & 0x1FFFF) * 32 + l];
    int dl = (e >> 17) & 63;
    float4 h = hl4[dl * 16 + l];
    h.x += __uint_as_float(v.x << 16);
    h.y += __uint_as_float(v.x & 0xFFFF0000u);
    h.z += __uint_as_float(v.y << 16);
    h.w += __uint_as_float(v.y & 0xFFFF0000u);
    hl4[dl * 16 + l] = h;
  }

  // ---- Overflow replay (expected ~12 entries globally), owner-routed ----
  __syncthreads();                       // stage D done; lists reusable
  int nov = min(*ovf_cnt, OVCAP);
  if (nov > 0) {
    int2* ovbuf = (int2*)lists;          // reuse lists memory (<=800 int2)
    for (int base = 0; base < nov; base += 800) {
      int m = min(nov - base, 800);
      for (int i = tid; i < m; i += 256) ovbuf[i] = ovf[base + i];
      __syncthreads();
      for (int i = 0; i < m; ++i) {
        int2 oe = ovbuf[i];
        if (oe.y == bb && (((oe.x >> 17) & 15) == g)) {
          uint2 v = ybh[(size_t)(oe.x & 0x1FFFF) * 32 + l];
          int dl = (oe.x >> 17) & 63;
          float4 h = hl4[dl * 16 + l];
          h.x += __uint_as_float(v.x << 16);
          h.y += __uint_as_float(v.x & 0xFFFF0000u);
          h.z += __uint_as_float(v.y << 16);
          h.w += __uint_as_float(v.y & 0xFFFF0000u);
          hl4[dl * 16 + l] = h;
        }
      }
      __syncthreads();
    }
  }
  __syncthreads();

  // ---- Stage E': out = relu(hl + b), coalesced float4 stores ----
  int c4 = tid & 15;                     // float4 col within half-row
  float4 bv = ((const float4*)b)[fh * 16 + c4];
  int row0 = bb * 64;
#pragma unroll
  for (int it = 0; it < 4; ++it) {
    int i = it * 256 + tid;
    int rl = i >> 4;                     // 0..63
    int row = row0 + rl;
    if (row < N) {
      float4 h = hl4[rl * 16 + c4];
      float4 o;
      o.x = fmaxf(h.x + bv.x, 0.f);
      o.y = fmaxf(h.y + bv.y, 0.f);
      o.z = fmaxf(h.z + bv.z, 0.f);
      o.w = fmaxf(h.w + bv.w, 0.f);
      ((float4*)out)[(size_t)row * (F / 4) + fh * 16 + c4] = o;
    }
  }
}

// ---------------------------------------------------------------------------
extern "C" void kernel_launch(void* const* d_in, const int* in_sizes, int n_in,
                              void* d_out, int out_size, void* d_ws, size_t ws_size,
                              hipStream_t stream) {
  const float* feat = (const float*)d_in[0];   // [N, D]
  const float* W    = (const float*)d_in[1];   // [D, F]
  const float* bv   = (const float*)d_in[2];   // [F]
  const int* src    = (const int*)d_in[3];     // [E]
  const int* dst    = (const int*)d_in[4];     // [E]

  int N = in_sizes[0] / D;
  int E = in_sizes[3];

  int NB = (N + 63) / 64;                      // buckets (1563; <= NBF)
  int CH = (E + NCH - 1) / NCH;                // edges per chunk (8334)
  int NU = (N + 255) / 256;                    // gemmy units (391)

  // Workspace layout (ws >= 51.2MB known from round 1):
  //   yb      [N*F bf16]           @ 0        (25.6MB)  <- Y = X@W
  //   gcnt    [NCH*NB ints]        @ 26MB     (~1.2MB)
  //   ovf_cnt [1 int]              @ 28MB
  //   ovf     [OVCAP int2]         @ 28MB+256 (128KB)
  //   gslot   [NCH*NB*CAPC ints]   @ 29MB     (19.2MB, chunk-major)
  uint2* yb     = (uint2*)d_ws;
  int* gcnt     = (int*)((char*)d_ws + (26u << 20));
  int* ovf_cnt  = (int*)((char*)d_ws + (28u << 20));
  int2* ovf     = (int2*)((char*)d_ws + (28u << 20) + 256);
  int* gslot    = (int*)((char*)d_ws + (29u << 20));

  float* out = (float*)d_out;

  hipMemsetAsync(ovf_cnt, 0, sizeof(int), stream);

  megaprep_kernel<<<NCH + NU, 1024, 0, stream>>>(
      src, dst, gcnt, gslot, ovf_cnt, ovf, feat, W, yb, E, NB, CH, N);

  accum_kernel<<<2 * NB, 256, 0, stream>>>(yb, gcnt, gslot, ovf_cnt, ovf,
                                           bv, out, N, NB);
}